// Round 13
// baseline (567.733 us; speedup 1.0000x reference)
//
#include <hip/hip_runtime.h>
#include <hip/hip_fp8.h>

#define N_NODES 100000
#define N_EDGES 1600000
#define BN_EPS 1e-5f
#define NB_SCAN 98       // ceil(100000/1024)
#define PART_SZ 12500    // N_NODES / 8 XCD partitions
#define FILL_CHUNKS 1024
#define CHUNK_SZ 1563    // ceil(N_EDGES / FILL_CHUNKS)

// broadcast lane k's value (readlane). Wave-uniform control flow ONLY.
__device__ __forceinline__ float bcast(float v, int k) {
    return __uint_as_float(__builtin_amdgcn_readlane(__float_as_uint(v), k));
}
__device__ __forceinline__ float bf16lo(unsigned int w) {
    return __uint_as_float(w << 16);
}
__device__ __forceinline__ float bf16hi(unsigned int w) {
    return __uint_as_float(w & 0xFFFF0000u);
}
__device__ __forceinline__ unsigned short f2bf(float x) {   // round-nearest-even
    unsigned int u = __float_as_uint(x);
    return (unsigned short)((u + 0x7FFF + ((u >> 16) & 1)) >> 16);
}
// fp8 e4m3 (OCP) decode/encode via HIP API (HW v_cvt on gfx950)
__device__ __forceinline__ float fp8d(unsigned int b) {
    __half_raw hr = __hip_cvt_fp8_to_halfraw((__hip_fp8_storage_t)b, __HIP_E4M3);
    return __half2float(__half(hr));
}
__device__ __forceinline__ unsigned char f2fp8(float x) {
    return (unsigned char)__hip_cvt_float_to_fp8(x, __HIP_SATFINITE, __HIP_E4M3);
}

// ===========================================================================
// CSR build, XCD-partitioned (R10, proven).
// ===========================================================================
__global__ __launch_bounds__(256) void histogram_xcd_kernel(
    const int* __restrict__ dst, int* __restrict__ deg)
{
    int part  = blockIdx.x & 7;
    int lo = part * PART_SZ, hi = lo + PART_SZ;
    int base  = (blockIdx.x >> 3) * CHUNK_SZ;
    int endE  = min(base + CHUNK_SZ, N_EDGES);
    for (int e = base + threadIdx.x; e < endE; e += 256) {
        int d = dst[e];
        if (d >= lo && d < hi) atomicAdd(&deg[d], 1);
    }
}

__global__ __launch_bounds__(256) void fill_xcd_kernel(
    const int* __restrict__ src, const int* __restrict__ dst,
    int* __restrict__ cursor, int* __restrict__ nbr)
{
    int part  = blockIdx.x & 7;
    int lo = part * PART_SZ, hi = lo + PART_SZ;
    int base  = (blockIdx.x >> 3) * CHUNK_SZ;
    int endE  = min(base + CHUNK_SZ, N_EDGES);
    for (int e = base + threadIdx.x; e < endE; e += 256) {
        int d = dst[e];
        if (d >= lo && d < hi) {
            int p = atomicAdd(&cursor[d], 1);
            nbr[p] = src[e];
        }
    }
}

__global__ __launch_bounds__(1024) void scan1_kernel(
    const int* __restrict__ deg, int* __restrict__ offs, int* __restrict__ bsum)
{
    __shared__ int tmp[1024];
    int gid = blockIdx.x * 1024 + threadIdx.x;
    int v = (gid < N_NODES) ? deg[gid] : 0;
    tmp[threadIdx.x] = v;
    __syncthreads();
    for (int off = 1; off < 1024; off <<= 1) {
        int t = (threadIdx.x >= off) ? tmp[threadIdx.x - off] : 0;
        __syncthreads();
        tmp[threadIdx.x] += t;
        __syncthreads();
    }
    if (gid < N_NODES) offs[gid] = tmp[threadIdx.x] - v;
    if (threadIdx.x == 1023) bsum[blockIdx.x] = tmp[1023];
}

// scan3b: each block redundantly reduces bsum for its base offset.
__global__ __launch_bounds__(1024) void scan3b_kernel(
    int* __restrict__ offs, const int* __restrict__ bsum, int* __restrict__ cursor)
{
    __shared__ int red[128];
    int tid = threadIdx.x;
    if (tid < 128) red[tid] = (tid < (int)blockIdx.x && tid < NB_SCAN) ? bsum[tid] : 0;
    __syncthreads();
    if (tid < 64) red[tid] += red[tid + 64];
    __syncthreads();
    if (tid < 32) red[tid] += red[tid + 32];
    __syncthreads();
    if (tid < 16) red[tid] += red[tid + 16];
    __syncthreads();
    if (tid < 8)  red[tid] += red[tid + 8];
    __syncthreads();
    if (tid < 4)  red[tid] += red[tid + 4];
    __syncthreads();
    if (tid < 2)  red[tid] += red[tid + 2];
    __syncthreads();
    if (tid == 0) red[0] += red[1];
    __syncthreads();
    int base = red[0];
    int gid = blockIdx.x * 1024 + tid;
    if (gid < N_NODES) {
        int v = offs[gid] + base;
        offs[gid] = v;
        cursor[gid] = v;
    }
    if (gid == N_NODES) offs[N_NODES] = N_EDGES;
}

// ===========================================================================
// dense1_lin: u(fp8 e4m3, 64B rows = 1 line) = x @ W1l^T ;
// hv(f32) = x @ W1r^T + b1.
// ===========================================================================
__global__ __launch_bounds__(256) void dense1_lin_kernel(
    const float* __restrict__ x, const float* __restrict__ W1l,
    const float* __restrict__ W1r, const float* __restrict__ b1,
    unsigned char* __restrict__ u8, float* __restrict__ hv)
{
    __shared__ float wlT[64 * 65];
    __shared__ float wrT[64 * 65];
    for (int idx = threadIdx.x; idx < 4096; idx += 256) {
        int f = idx >> 6, k = idx & 63;
        wlT[k * 65 + f] = W1l[idx];
        wrT[k * 65 + f] = W1r[idx];
    }
    __syncthreads();

    int f  = threadIdx.x & 63;
    int wv = threadIdx.x >> 6;
    float wl[64], wr[64];
#pragma unroll
    for (int k = 0; k < 64; ++k) {
        wl[k] = wlT[k * 65 + f];
        wr[k] = wrT[k * 65 + f];
    }
    float bias = b1[f];
    int node0 = blockIdx.x * 64;

    for (int nn = 0; nn < 16; ++nn) {
        int node = node0 + nn * 4 + wv;          // wave-uniform
        if (node < N_NODES) {
            float xv = x[(size_t)node * 64 + f];
            float ua = 0.f, va = bias;
#pragma unroll
            for (int k = 0; k < 64; ++k) {
                float xb = bcast(xv, k);
                ua += xb * wl[k];
                va += xb * wr[k];
            }
            u8[(size_t)node * 64 + f] = f2fp8(ua);   // coalesced 64B/node
            hv[(size_t)node * 64 + f] = va;
        }
    }
}

// ===========================================================================
// gather1_bn v7 = v3 shape (proven local optimum: half-wave edge pairs, one
// coalesced id load per 64-edge chunk, ids via shfl, 16 nodes/wave) with u
// in fp8: row = 64B = ONE line per edge (was 2 with bf16) -> halves the
// expensive random L2-line requests that bind this kernel.
// Lane m loads ushort = features 2m,2m+1 of one edge; 32 lanes = full row.
// ===========================================================================
__global__ __launch_bounds__(256) void gather1_bn_kernel(
    const unsigned short* __restrict__ u16, const int* __restrict__ offs,
    const int* __restrict__ nbr, float* __restrict__ hv,
    float* __restrict__ sums, float* __restrict__ sumsq)
{
    int lane = threadIdx.x & 63;
    int m    = lane & 31;
    int half = lane >> 5;
    int wv   = threadIdx.x >> 6;
    int node0 = blockIdx.x * 64;
    float s1_0 = 0.f, s1_1 = 0.f, s2_0 = 0.f, s2_1 = 0.f;

    for (int nn = 0; nn < 16; ++nn) {
        int node = node0 + nn * 4 + wv;
        if (node < N_NODES) {                    // wave-uniform
            int beg = offs[node], end = offs[node + 1];
            int deg = end - beg;
            float p0=0,p1=0,p2=0,p3=0,q0=0,q1=0,q2=0,q3=0;
            for (int c = 0; c < deg; c += 64) {  // ~always 1 iteration
                int idx = beg + c + lane;
                int id  = nbr[(idx < end) ? idx : (end - 1)];  // coalesced
                int cnt = min(deg - c, 64);
                for (int r = 0; r < cnt; r += 16) {   // wave-uniform trips
#pragma unroll
                    for (int i = 0; i < 8; ++i) {
                        int e   = r + 2 * i + half;   // < 64 always
                        int ide = __shfl(id, e);      // id from registers
                        unsigned int w = u16[(size_t)ide * 32 + m];
                        bool val = (e < cnt);
                        float lo = val ? fp8d(w & 0xFFu) : 0.f;
                        float hi = val ? fp8d(w >> 8)    : 0.f;
                        if ((i & 3) == 0)      { p0 += lo; q0 += hi; }
                        else if ((i & 3) == 1) { p1 += lo; q1 += hi; }
                        else if ((i & 3) == 2) { p2 += lo; q2 += hi; }
                        else                   { p3 += lo; q3 += hi; }
                    }
                }
            }
            float P = (p0 + p1) + (p2 + p3);
            float Q = (q0 + q1) + (q2 + q3);
            P += __shfl_xor(P, 32);    // combine the two half-waves
            Q += __shfl_xor(Q, 32);
            if (half == 0) {
                float inv = 1.0f / (float)max(deg, 1);
                float2 v = ((const float2*)hv)[(size_t)node * 32 + m];
                float h0 = P * inv + v.x;
                float h1 = Q * inv + v.y;
                ((float2*)hv)[(size_t)node * 32 + m] = make_float2(h0, h1);
                s1_0 += h0; s1_1 += h1;
                s2_0 += h0 * h0; s2_1 += h1 * h1;
            }
        }
    }

    __shared__ float2 redA[256];
    __shared__ float2 redB[256];
    redA[threadIdx.x] = make_float2(s1_0, s1_1);
    redB[threadIdx.x] = make_float2(s2_0, s2_1);
    __syncthreads();
    if (threadIdx.x < 32) {
        int mm = threadIdx.x;
        float a0=0,a1=0,b0=0,b1=0;
        for (int w = 0; w < 4; ++w) {
            float2 A = redA[w * 64 + mm]; a0 += A.x; a1 += A.y;
            float2 B = redB[w * 64 + mm]; b0 += B.x; b1 += B.y;
        }
        atomicAdd(&sums[2 * mm], a0);  atomicAdd(&sums[2 * mm + 1], a1);
        atomicAdd(&sumsq[2 * mm], b0); atomicAdd(&sumsq[2 * mm + 1], b1);
    }
}

// ===========================================================================
// dense2_bn: BN finalize folded in; BN+ReLU per lane; projections split:
// tmp32 (32 bf16 = 64B rows) + tmp8 (8 bf16 = 16B rows) for the gather;
// out = hn @ W2r^T + b2 written directly. (R12, proven)
// ===========================================================================
__global__ __launch_bounds__(256) void dense2_bn_kernel(
    const float* __restrict__ h, const float* __restrict__ sums,
    const float* __restrict__ sumsq, const float* __restrict__ gamma,
    const float* __restrict__ beta, const float* __restrict__ W2l,
    const float* __restrict__ W2r, const float* __restrict__ b2,
    unsigned short* __restrict__ tmp32, unsigned short* __restrict__ tmp8,
    float* __restrict__ out)
{
    __shared__ float wlT[64 * 65];
    __shared__ float wrT[64 * 65];
    for (int idx = threadIdx.x; idx < 2560; idx += 256) {
        int f = idx >> 6, k = idx & 63;      // f < 40
        wlT[k * 65 + f] = W2l[idx];
        wrT[k * 65 + f] = W2r[idx];
    }
    __syncthreads();

    int f  = threadIdx.x & 63;
    int wv = threadIdx.x >> 6;
    int fc = (f < 40) ? f : 39;
    float wl[64], wr[64];
#pragma unroll
    for (int k = 0; k < 64; ++k) {
        wl[k] = wlT[k * 65 + fc];
        wr[k] = wrT[k * 65 + fc];
    }
    float bias = b2[fc];

    // BN finalize (redundant per block, ~10 insts)
    float inv_n = 1.0f / (float)N_NODES;
    float mu  = sums[f] * inv_n;
    float var = sumsq[f] * inv_n - mu * mu;
    float rs  = rsqrtf(var + BN_EPS);
    float sc  = gamma[f] * rs;
    float sh  = beta[f] - mu * sc;

    int node0 = blockIdx.x * 64;

    for (int nn = 0; nn < 16; ++nn) {
        int node = node0 + nn * 4 + wv;          // wave-uniform
        if (node < N_NODES) {
            float hvv = h[(size_t)node * 64 + f];
            float hn  = fmaxf(hvv * sc + sh, 0.f);   // BN + ReLU fused
            float ta = 0.f, ra = bias;
#pragma unroll
            for (int k = 0; k < 64; ++k) {
                float hb = bcast(hn, k);
                ta += hb * wl[k];
                ra += hb * wr[k];
            }
            if (f < 32) {
                tmp32[(size_t)node * 32 + f] = f2bf(ta);
            } else if (f < 40) {
                tmp8[(size_t)node * 8 + (f - 32)] = f2bf(ta);
            }
            if (f < 40) out[(size_t)node * 40 + f] = ra;
        }
    }
}

// ===========================================================================
// gather2 v6 (R12, proven): out += mean over neighbors of [tmp32 | tmp8].
// ===========================================================================
__global__ __launch_bounds__(256) void gather2_kernel(
    const unsigned int* __restrict__ t32, const unsigned int* __restrict__ t8,
    const int* __restrict__ offs, const int* __restrict__ nbr,
    float* __restrict__ out)
{
    int lane = threadIdx.x & 63;
    int q    = lane >> 4;       // quarter 0..3
    int m    = lane & 15;       // dword in 64B row (feats 2m, 2m+1)
    int j    = lane & 3;        // dword in 16B row (feats 32+2j, 33+2j)
    int g    = lane >> 2;       // edge-group for tmp8 (0..15)
    int wv   = threadIdx.x >> 6;
    int node0 = blockIdx.x * 64;

    for (int nn = 0; nn < 16; ++nn) {
        int node = node0 + nn * 4 + wv;
        if (node < N_NODES) {                    // wave-uniform
            int beg = offs[node], end = offs[node + 1];
            int deg = end - beg;
            float p0=0,p1=0,p2=0,p3=0;           // tmp32 partials
            float e8a=0, e8b=0;                  // tmp8 partials
            for (int c = 0; c < deg; c += 64) {
                int idx = beg + c + lane;
                int id  = nbr[(idx < end) ? idx : (end - 1)];  // coalesced
                int cnt = min(deg - c, 64);
                for (int r = 0; r < cnt; r += 16) {
#pragma unroll
                    for (int i = 0; i < 4; ++i) {           // tmp32: 4x4 edges
                        int e   = r + 4 * i + q;
                        int ide = __shfl(id, min(e, cnt - 1));
                        unsigned int w = t32[(size_t)ide * 16 + m];
                        bool val = (e < cnt);
                        float lo = val ? bf16lo(w) : 0.f;
                        float hi = val ? bf16hi(w) : 0.f;
                        if (i & 1) { p2 += lo; p3 += hi; }
                        else       { p0 += lo; p1 += hi; }
                    }
                    {                                        // tmp8: 16 edges
                        int e   = r + g;
                        int ide = __shfl(id, min(e, cnt - 1));
                        unsigned int w = t8[(size_t)ide * 4 + j];
                        bool val = (e < cnt);
                        e8a += val ? bf16lo(w) : 0.f;
                        e8b += val ? bf16hi(w) : 0.f;
                    }
                }
            }
            float P0 = p0 + p2, P1 = p1 + p3;
            P0 += __shfl_xor(P0, 16); P0 += __shfl_xor(P0, 32);
            P1 += __shfl_xor(P1, 16); P1 += __shfl_xor(P1, 32);
            e8a += __shfl_xor(e8a, 4);  e8a += __shfl_xor(e8a, 8);
            e8a += __shfl_xor(e8a, 16); e8a += __shfl_xor(e8a, 32);
            e8b += __shfl_xor(e8b, 4);  e8b += __shfl_xor(e8b, 8);
            e8b += __shfl_xor(e8b, 16); e8b += __shfl_xor(e8b, 32);
            float inv = 1.0f / (float)max(deg, 1);
            if (lane < 16) {
                float2 o = ((float2*)out)[(size_t)node * 20 + m];
                o.x += P0 * inv;
                o.y += P1 * inv;
                ((float2*)out)[(size_t)node * 20 + m] = o;
            } else if (lane < 20) {      // lanes 16..19 have j=0..3 totals
                float2 o = ((float2*)out)[(size_t)node * 20 + 16 + j];
                o.x += e8a * inv;
                o.y += e8b * inv;
                ((float2*)out)[(size_t)node * 20 + 16 + j] = o;
            }
        }
    }
}

extern "C" void kernel_launch(void* const* d_in, const int* in_sizes, int n_in,
                              void* d_out, int out_size, void* d_ws, size_t ws_size,
                              hipStream_t stream)
{
    const float* x     = (const float*)d_in[0];
    const int*   ei    = (const int*)d_in[1];
    const float* W1l   = (const float*)d_in[2];
    const float* W1r   = (const float*)d_in[3];
    const float* b1    = (const float*)d_in[4];
    const float* gamma = (const float*)d_in[5];
    const float* beta  = (const float*)d_in[6];
    const float* W2l   = (const float*)d_in[7];
    const float* W2r   = (const float*)d_in[8];
    const float* b2    = (const float*)d_in[9];
    float* out = (float*)d_out;

    const int* src = ei;
    const int* dst = ei + N_EDGES;

    // workspace layout (~41 MB; 58.8 MB available). 64B-aligned arrays.
    float* ws    = (float*)d_ws;
    float* hv    = ws;                               // f32 [N*64]
    float* sums  = hv + (size_t)N_NODES * 64;        // 64
    float* sumsq = sums + 64;                        // 64
    float* padf  = sumsq + 64;                       // 128 pad
    int* deg    = (int*)(padf + 128);                // N
    int* offs   = deg + N_NODES;                     // N+16 (padded)
    int* cursor = offs + N_NODES + 16;               // N
    int* bsum   = cursor + N_NODES;                  // 128
    // scratch region: u (fp8 N*64 = 6.4MB) lives until gather1; then
    // tmp32/tmp8 (8MB) are written by dense2. Sized for the max (8MB).
    unsigned char* u8 = (unsigned char*)(bsum + 128);
    unsigned short* t32v = (unsigned short*)u8;          // bf16 [N*32]
    unsigned short* t8v  = t32v + (size_t)N_NODES * 32;  // bf16 [N*8]
    int* nbr    = (int*)(t8v + (size_t)N_NODES * 8);     // E

    dim3 blk(256);

    // ---- CSR build (XCD-partitioned) + BN-stat zeroing: 1 memset ----
    hipMemsetAsync(sums, 0, (size_t)(256 + N_NODES) * sizeof(int), stream);
    histogram_xcd_kernel<<<FILL_CHUNKS * 8, blk, 0, stream>>>(dst, deg);
    scan1_kernel<<<NB_SCAN, 1024, 0, stream>>>(deg, offs, bsum);
    scan3b_kernel<<<NB_SCAN, 1024, 0, stream>>>(offs, bsum, cursor);
    fill_xcd_kernel<<<FILL_CHUNKS * 8, blk, 0, stream>>>(src, dst, cursor, nbr);

    int dblocks = (N_NODES + 63) / 64;
    int gblocks = (N_NODES + 63) / 64;

    // ---- layer 1 ----
    dense1_lin_kernel<<<dblocks, blk, 0, stream>>>(x, W1l, W1r, b1, u8, hv);
    gather1_bn_kernel<<<gblocks, blk, 0, stream>>>(
        (const unsigned short*)u8, offs, nbr, hv, sums, sumsq);

    // ---- layer 2 (BN finalize + BN+ReLU fused into dense2) ----
    dense2_bn_kernel<<<dblocks, blk, 0, stream>>>(
        hv, sums, sumsq, gamma, beta, W2l, W2r, b2, t32v, t8v, out);
    gather2_kernel<<<gblocks, blk, 0, stream>>>(
        (const unsigned int*)t32v, (const unsigned int*)t8v, offs, nbr, out);
}

// Round 14
// 500.182 us; speedup vs baseline: 1.1351x; 1.1351x over previous
//
#include <hip/hip_runtime.h>
#include <hip/hip_fp8.h>

#define N_NODES 100000
#define N_EDGES 1600000
#define BN_EPS 1e-5f
#define NB_SCAN 98       // ceil(100000/1024)
#define PART_SZ 12500    // N_NODES / 8 XCD partitions
#define FILL_CHUNKS 1024
#define CHUNK_SZ 1563    // ceil(N_EDGES / FILL_CHUNKS)

typedef float v2f __attribute__((ext_vector_type(2)));

// broadcast lane k's value (readlane). Wave-uniform control flow ONLY.
__device__ __forceinline__ float bcast(float v, int k) {
    return __uint_as_float(__builtin_amdgcn_readlane(__float_as_uint(v), k));
}
__device__ __forceinline__ float bf16lo(unsigned int w) {
    return __uint_as_float(w << 16);
}
__device__ __forceinline__ float bf16hi(unsigned int w) {
    return __uint_as_float(w & 0xFFFF0000u);
}
__device__ __forceinline__ unsigned short f2bf(float x) {   // round-nearest-even
    unsigned int u = __float_as_uint(x);
    return (unsigned short)((u + 0x7FFF + ((u >> 16) & 1)) >> 16);
}
// fp8 e4m3 encode (cold path: once per element, in dense1)
__device__ __forceinline__ unsigned char f2fp8(float x) {
    return (unsigned char)__hip_cvt_float_to_fp8(x, __HIP_SATFINITE, __HIP_E4M3);
}
// HW packed decode: 2 x fp8(e4m3) -> 2 x f32 in ONE VALU instruction
// (v_cvt_pk_f32_fp8, gfx940+). R13 used the HIP API here -> ~25 VALU
// ops/pair -> VALUBusy 47% -> regression. This is the fix.
__device__ __forceinline__ v2f fp8x2(unsigned int w) {
#if __has_builtin(__builtin_amdgcn_cvt_pk_f32_fp8)
    return __builtin_amdgcn_cvt_pk_f32_fp8((int)w, false);
#else
    __half_raw h0 = __hip_cvt_fp8_to_halfraw((__hip_fp8_storage_t)(w & 0xFF), __HIP_E4M3);
    __half_raw h1 = __hip_cvt_fp8_to_halfraw((__hip_fp8_storage_t)((w >> 8) & 0xFF), __HIP_E4M3);
    v2f r; r.x = __half2float(__half(h0)); r.y = __half2float(__half(h1));
    return r;
#endif
}

// ===========================================================================
// CSR build, XCD-partitioned (R10, proven).
// ===========================================================================
__global__ __launch_bounds__(256) void histogram_xcd_kernel(
    const int* __restrict__ dst, int* __restrict__ deg)
{
    int part  = blockIdx.x & 7;
    int lo = part * PART_SZ, hi = lo + PART_SZ;
    int base  = (blockIdx.x >> 3) * CHUNK_SZ;
    int endE  = min(base + CHUNK_SZ, N_EDGES);
    for (int e = base + threadIdx.x; e < endE; e += 256) {
        int d = dst[e];
        if (d >= lo && d < hi) atomicAdd(&deg[d], 1);
    }
}

__global__ __launch_bounds__(256) void fill_xcd_kernel(
    const int* __restrict__ src, const int* __restrict__ dst,
    int* __restrict__ cursor, int* __restrict__ nbr)
{
    int part  = blockIdx.x & 7;
    int lo = part * PART_SZ, hi = lo + PART_SZ;
    int base  = (blockIdx.x >> 3) * CHUNK_SZ;
    int endE  = min(base + CHUNK_SZ, N_EDGES);
    for (int e = base + threadIdx.x; e < endE; e += 256) {
        int d = dst[e];
        if (d >= lo && d < hi) {
            int p = atomicAdd(&cursor[d], 1);
            nbr[p] = src[e];
        }
    }
}

__global__ __launch_bounds__(1024) void scan1_kernel(
    const int* __restrict__ deg, int* __restrict__ offs, int* __restrict__ bsum)
{
    __shared__ int tmp[1024];
    int gid = blockIdx.x * 1024 + threadIdx.x;
    int v = (gid < N_NODES) ? deg[gid] : 0;
    tmp[threadIdx.x] = v;
    __syncthreads();
    for (int off = 1; off < 1024; off <<= 1) {
        int t = (threadIdx.x >= off) ? tmp[threadIdx.x - off] : 0;
        __syncthreads();
        tmp[threadIdx.x] += t;
        __syncthreads();
    }
    if (gid < N_NODES) offs[gid] = tmp[threadIdx.x] - v;
    if (threadIdx.x == 1023) bsum[blockIdx.x] = tmp[1023];
}

// scan3b: each block redundantly reduces bsum for its base offset.
__global__ __launch_bounds__(1024) void scan3b_kernel(
    int* __restrict__ offs, const int* __restrict__ bsum, int* __restrict__ cursor)
{
    __shared__ int red[128];
    int tid = threadIdx.x;
    if (tid < 128) red[tid] = (tid < (int)blockIdx.x && tid < NB_SCAN) ? bsum[tid] : 0;
    __syncthreads();
    if (tid < 64) red[tid] += red[tid + 64];
    __syncthreads();
    if (tid < 32) red[tid] += red[tid + 32];
    __syncthreads();
    if (tid < 16) red[tid] += red[tid + 16];
    __syncthreads();
    if (tid < 8)  red[tid] += red[tid + 8];
    __syncthreads();
    if (tid < 4)  red[tid] += red[tid + 4];
    __syncthreads();
    if (tid < 2)  red[tid] += red[tid + 2];
    __syncthreads();
    if (tid == 0) red[0] += red[1];
    __syncthreads();
    int base = red[0];
    int gid = blockIdx.x * 1024 + tid;
    if (gid < N_NODES) {
        int v = offs[gid] + base;
        offs[gid] = v;
        cursor[gid] = v;
    }
    if (gid == N_NODES) offs[N_NODES] = N_EDGES;
}

// ===========================================================================
// dense1_lin: u(fp8 e4m3, 64B rows = 1 line) = x @ W1l^T ;
// hv(f32) = x @ W1r^T + b1.
// ===========================================================================
__global__ __launch_bounds__(256) void dense1_lin_kernel(
    const float* __restrict__ x, const float* __restrict__ W1l,
    const float* __restrict__ W1r, const float* __restrict__ b1,
    unsigned char* __restrict__ u8, float* __restrict__ hv)
{
    __shared__ float wlT[64 * 65];
    __shared__ float wrT[64 * 65];
    for (int idx = threadIdx.x; idx < 4096; idx += 256) {
        int f = idx >> 6, k = idx & 63;
        wlT[k * 65 + f] = W1l[idx];
        wrT[k * 65 + f] = W1r[idx];
    }
    __syncthreads();

    int f  = threadIdx.x & 63;
    int wv = threadIdx.x >> 6;
    float wl[64], wr[64];
#pragma unroll
    for (int k = 0; k < 64; ++k) {
        wl[k] = wlT[k * 65 + f];
        wr[k] = wrT[k * 65 + f];
    }
    float bias = b1[f];
    int node0 = blockIdx.x * 64;

    for (int nn = 0; nn < 16; ++nn) {
        int node = node0 + nn * 4 + wv;          // wave-uniform
        if (node < N_NODES) {
            float xv = x[(size_t)node * 64 + f];
            float ua = 0.f, va = bias;
#pragma unroll
            for (int k = 0; k < 64; ++k) {
                float xb = bcast(xv, k);
                ua += xb * wl[k];
                va += xb * wr[k];
            }
            u8[(size_t)node * 64 + f] = f2fp8(ua);   // coalesced 64B/node
            hv[(size_t)node * 64 + f] = va;
        }
    }
}

// ===========================================================================
// gather1_bn v8 = v3 shape + fp8 rows (1 line/edge) + HW packed decode.
// Lane m loads ushort = features 2m,2m+1; invalid edges zero the packed
// word (one cndmask; fp8 0x00 == 0.0) before the single v_cvt_pk_f32_fp8.
// ===========================================================================
__global__ __launch_bounds__(256) void gather1_bn_kernel(
    const unsigned short* __restrict__ u16, const int* __restrict__ offs,
    const int* __restrict__ nbr, float* __restrict__ hv,
    float* __restrict__ sums, float* __restrict__ sumsq)
{
    int lane = threadIdx.x & 63;
    int m    = lane & 31;
    int half = lane >> 5;
    int wv   = threadIdx.x >> 6;
    int node0 = blockIdx.x * 64;
    float s1_0 = 0.f, s1_1 = 0.f, s2_0 = 0.f, s2_1 = 0.f;

    for (int nn = 0; nn < 16; ++nn) {
        int node = node0 + nn * 4 + wv;
        if (node < N_NODES) {                    // wave-uniform
            int beg = offs[node], end = offs[node + 1];
            int deg = end - beg;
            float p0=0,p1=0,p2=0,p3=0,q0=0,q1=0,q2=0,q3=0;
            for (int c = 0; c < deg; c += 64) {  // ~always 1 iteration
                int idx = beg + c + lane;
                int id  = nbr[(idx < end) ? idx : (end - 1)];  // coalesced
                int cnt = min(deg - c, 64);
                for (int r = 0; r < cnt; r += 16) {   // wave-uniform trips
#pragma unroll
                    for (int i = 0; i < 8; ++i) {
                        int e   = r + 2 * i + half;   // < 64 always
                        int ide = __shfl(id, e);      // id from registers
                        unsigned int w = u16[(size_t)ide * 32 + m];
                        w = (e < cnt) ? w : 0u;       // mask packed word
                        v2f d = fp8x2(w);             // 1 HW instruction
                        if ((i & 3) == 0)      { p0 += d.x; q0 += d.y; }
                        else if ((i & 3) == 1) { p1 += d.x; q1 += d.y; }
                        else if ((i & 3) == 2) { p2 += d.x; q2 += d.y; }
                        else                   { p3 += d.x; q3 += d.y; }
                    }
                }
            }
            float P = (p0 + p1) + (p2 + p3);
            float Q = (q0 + q1) + (q2 + q3);
            P += __shfl_xor(P, 32);    // combine the two half-waves
            Q += __shfl_xor(Q, 32);
            if (half == 0) {
                float inv = 1.0f / (float)max(deg, 1);
                float2 v = ((const float2*)hv)[(size_t)node * 32 + m];
                float h0 = P * inv + v.x;
                float h1 = Q * inv + v.y;
                ((float2*)hv)[(size_t)node * 32 + m] = make_float2(h0, h1);
                s1_0 += h0; s1_1 += h1;
                s2_0 += h0 * h0; s2_1 += h1 * h1;
            }
        }
    }

    __shared__ float2 redA[256];
    __shared__ float2 redB[256];
    redA[threadIdx.x] = make_float2(s1_0, s1_1);
    redB[threadIdx.x] = make_float2(s2_0, s2_1);
    __syncthreads();
    if (threadIdx.x < 32) {
        int mm = threadIdx.x;
        float a0=0,a1=0,b0=0,b1=0;
        for (int w = 0; w < 4; ++w) {
            float2 A = redA[w * 64 + mm]; a0 += A.x; a1 += A.y;
            float2 B = redB[w * 64 + mm]; b0 += B.x; b1 += B.y;
        }
        atomicAdd(&sums[2 * mm], a0);  atomicAdd(&sums[2 * mm + 1], a1);
        atomicAdd(&sumsq[2 * mm], b0); atomicAdd(&sumsq[2 * mm + 1], b1);
    }
}

// ===========================================================================
// dense2_bn: BN finalize folded in; BN+ReLU per lane; projections split:
// tmp32 (32 bf16 = 64B rows) + tmp8 (8 bf16 = 16B rows); out direct. (R12)
// ===========================================================================
__global__ __launch_bounds__(256) void dense2_bn_kernel(
    const float* __restrict__ h, const float* __restrict__ sums,
    const float* __restrict__ sumsq, const float* __restrict__ gamma,
    const float* __restrict__ beta, const float* __restrict__ W2l,
    const float* __restrict__ W2r, const float* __restrict__ b2,
    unsigned short* __restrict__ tmp32, unsigned short* __restrict__ tmp8,
    float* __restrict__ out)
{
    __shared__ float wlT[64 * 65];
    __shared__ float wrT[64 * 65];
    for (int idx = threadIdx.x; idx < 2560; idx += 256) {
        int f = idx >> 6, k = idx & 63;      // f < 40
        wlT[k * 65 + f] = W2l[idx];
        wrT[k * 65 + f] = W2r[idx];
    }
    __syncthreads();

    int f  = threadIdx.x & 63;
    int wv = threadIdx.x >> 6;
    int fc = (f < 40) ? f : 39;
    float wl[64], wr[64];
#pragma unroll
    for (int k = 0; k < 64; ++k) {
        wl[k] = wlT[k * 65 + fc];
        wr[k] = wrT[k * 65 + fc];
    }
    float bias = b2[fc];

    // BN finalize (redundant per block, ~10 insts)
    float inv_n = 1.0f / (float)N_NODES;
    float mu  = sums[f] * inv_n;
    float var = sumsq[f] * inv_n - mu * mu;
    float rs  = rsqrtf(var + BN_EPS);
    float sc  = gamma[f] * rs;
    float sh  = beta[f] - mu * sc;

    int node0 = blockIdx.x * 64;

    for (int nn = 0; nn < 16; ++nn) {
        int node = node0 + nn * 4 + wv;          // wave-uniform
        if (node < N_NODES) {
            float hvv = h[(size_t)node * 64 + f];
            float hn  = fmaxf(hvv * sc + sh, 0.f);   // BN + ReLU fused
            float ta = 0.f, ra = bias;
#pragma unroll
            for (int k = 0; k < 64; ++k) {
                float hb = bcast(hn, k);
                ta += hb * wl[k];
                ra += hb * wr[k];
            }
            if (f < 32) {
                tmp32[(size_t)node * 32 + f] = f2bf(ta);
            } else if (f < 40) {
                tmp8[(size_t)node * 8 + (f - 32)] = f2bf(ta);
            }
            if (f < 40) out[(size_t)node * 40 + f] = ra;
        }
    }
}

// ===========================================================================
// gather2 v6 (R12, proven): out += mean over neighbors of [tmp32 | tmp8].
// ===========================================================================
__global__ __launch_bounds__(256) void gather2_kernel(
    const unsigned int* __restrict__ t32, const unsigned int* __restrict__ t8,
    const int* __restrict__ offs, const int* __restrict__ nbr,
    float* __restrict__ out)
{
    int lane = threadIdx.x & 63;
    int q    = lane >> 4;       // quarter 0..3
    int m    = lane & 15;       // dword in 64B row (feats 2m, 2m+1)
    int j    = lane & 3;        // dword in 16B row (feats 32+2j, 33+2j)
    int g    = lane >> 2;       // edge-group for tmp8 (0..15)
    int wv   = threadIdx.x >> 6;
    int node0 = blockIdx.x * 64;

    for (int nn = 0; nn < 16; ++nn) {
        int node = node0 + nn * 4 + wv;
        if (node < N_NODES) {                    // wave-uniform
            int beg = offs[node], end = offs[node + 1];
            int deg = end - beg;
            float p0=0,p1=0,p2=0,p3=0;           // tmp32 partials
            float e8a=0, e8b=0;                  // tmp8 partials
            for (int c = 0; c < deg; c += 64) {
                int idx = beg + c + lane;
                int id  = nbr[(idx < end) ? idx : (end - 1)];  // coalesced
                int cnt = min(deg - c, 64);
                for (int r = 0; r < cnt; r += 16) {
#pragma unroll
                    for (int i = 0; i < 4; ++i) {           // tmp32: 4x4 edges
                        int e   = r + 4 * i + q;
                        int ide = __shfl(id, min(e, cnt - 1));
                        unsigned int w = t32[(size_t)ide * 16 + m];
                        bool val = (e < cnt);
                        float lo = val ? bf16lo(w) : 0.f;
                        float hi = val ? bf16hi(w) : 0.f;
                        if (i & 1) { p2 += lo; p3 += hi; }
                        else       { p0 += lo; p1 += hi; }
                    }
                    {                                        // tmp8: 16 edges
                        int e   = r + g;
                        int ide = __shfl(id, min(e, cnt - 1));
                        unsigned int w = t8[(size_t)ide * 4 + j];
                        bool val = (e < cnt);
                        e8a += val ? bf16lo(w) : 0.f;
                        e8b += val ? bf16hi(w) : 0.f;
                    }
                }
            }
            float P0 = p0 + p2, P1 = p1 + p3;
            P0 += __shfl_xor(P0, 16); P0 += __shfl_xor(P0, 32);
            P1 += __shfl_xor(P1, 16); P1 += __shfl_xor(P1, 32);
            e8a += __shfl_xor(e8a, 4);  e8a += __shfl_xor(e8a, 8);
            e8a += __shfl_xor(e8a, 16); e8a += __shfl_xor(e8a, 32);
            e8b += __shfl_xor(e8b, 4);  e8b += __shfl_xor(e8b, 8);
            e8b += __shfl_xor(e8b, 16); e8b += __shfl_xor(e8b, 32);
            float inv = 1.0f / (float)max(deg, 1);
            if (lane < 16) {
                float2 o = ((float2*)out)[(size_t)node * 20 + m];
                o.x += P0 * inv;
                o.y += P1 * inv;
                ((float2*)out)[(size_t)node * 20 + m] = o;
            } else if (lane < 20) {      // lanes 16..19 have j=0..3 totals
                float2 o = ((float2*)out)[(size_t)node * 20 + 16 + j];
                o.x += e8a * inv;
                o.y += e8b * inv;
                ((float2*)out)[(size_t)node * 20 + 16 + j] = o;
            }
        }
    }
}

extern "C" void kernel_launch(void* const* d_in, const int* in_sizes, int n_in,
                              void* d_out, int out_size, void* d_ws, size_t ws_size,
                              hipStream_t stream)
{
    const float* x     = (const float*)d_in[0];
    const int*   ei    = (const int*)d_in[1];
    const float* W1l   = (const float*)d_in[2];
    const float* W1r   = (const float*)d_in[3];
    const float* b1    = (const float*)d_in[4];
    const float* gamma = (const float*)d_in[5];
    const float* beta  = (const float*)d_in[6];
    const float* W2l   = (const float*)d_in[7];
    const float* W2r   = (const float*)d_in[8];
    const float* b2    = (const float*)d_in[9];
    float* out = (float*)d_out;

    const int* src = ei;
    const int* dst = ei + N_EDGES;

    // workspace layout (~41 MB; 58.8 MB available). 64B-aligned arrays.
    float* ws    = (float*)d_ws;
    float* hv    = ws;                               // f32 [N*64]
    float* sums  = hv + (size_t)N_NODES * 64;        // 64
    float* sumsq = sums + 64;                        // 64
    float* padf  = sumsq + 64;                       // 128 pad
    int* deg    = (int*)(padf + 128);                // N
    int* offs   = deg + N_NODES;                     // N+16 (padded)
    int* cursor = offs + N_NODES + 16;               // N
    int* bsum   = cursor + N_NODES;                  // 128
    // scratch: u (fp8 N*64 = 6.4MB) until gather1; then tmp32/tmp8 (8MB).
    unsigned char* u8 = (unsigned char*)(bsum + 128);
    unsigned short* t32v = (unsigned short*)u8;          // bf16 [N*32]
    unsigned short* t8v  = t32v + (size_t)N_NODES * 32;  // bf16 [N*8]
    int* nbr    = (int*)(t8v + (size_t)N_NODES * 8);     // E

    dim3 blk(256);

    // ---- CSR build (XCD-partitioned) + BN-stat zeroing: 1 memset ----
    hipMemsetAsync(sums, 0, (size_t)(256 + N_NODES) * sizeof(int), stream);
    histogram_xcd_kernel<<<FILL_CHUNKS * 8, blk, 0, stream>>>(dst, deg);
    scan1_kernel<<<NB_SCAN, 1024, 0, stream>>>(deg, offs, bsum);
    scan3b_kernel<<<NB_SCAN, 1024, 0, stream>>>(offs, bsum, cursor);
    fill_xcd_kernel<<<FILL_CHUNKS * 8, blk, 0, stream>>>(src, dst, cursor, nbr);

    int dblocks = (N_NODES + 63) / 64;
    int gblocks = (N_NODES + 63) / 64;

    // ---- layer 1 ----
    dense1_lin_kernel<<<dblocks, blk, 0, stream>>>(x, W1l, W1r, b1, u8, hv);
    gather1_bn_kernel<<<gblocks, blk, 0, stream>>>(
        (const unsigned short*)u8, offs, nbr, hv, sums, sumsq);

    // ---- layer 2 (BN finalize + BN+ReLU fused into dense2) ----
    dense2_bn_kernel<<<dblocks, blk, 0, stream>>>(
        hv, sums, sumsq, gamma, beta, W2l, W2r, b2, t32v, t8v, out);
    gather2_kernel<<<gblocks, blk, 0, stream>>>(
        (const unsigned int*)t32v, (const unsigned int*)t8v, offs, nbr, out);
}

// Round 16
// 486.702 us; speedup vs baseline: 1.1665x; 1.0277x over previous
//
#include <hip/hip_runtime.h>
#include <hip/hip_fp8.h>

#define N_NODES 100000
#define N_EDGES 1600000
#define BN_EPS 1e-5f
#define NB_SCAN 98       // ceil(100000/1024)
#define PART_SZ 12500    // N_NODES / 8 XCD partitions
#define FILL_CHUNKS 1000
#define CHUNK_I4 400     // int4s per chunk: 1000 * 400 * 4 = 1.6M edges exact

typedef float v2f __attribute__((ext_vector_type(2)));

// broadcast lane k's value (readlane). Wave-uniform control flow ONLY.
__device__ __forceinline__ float bcast(float v, int k) {
    return __uint_as_float(__builtin_amdgcn_readlane(__float_as_uint(v), k));
}
__device__ __forceinline__ unsigned short f2bf(float x) {   // round-nearest-even
    unsigned int u = __float_as_uint(x);
    return (unsigned short)((u + 0x7FFF + ((u >> 16) & 1)) >> 16);
}
// fp8 e4m3 encode (cold path: once per element in the dense kernels)
__device__ __forceinline__ unsigned char f2fp8(float x) {
    return (unsigned char)__hip_cvt_float_to_fp8(x, __HIP_SATFINITE, __HIP_E4M3);
}
// HW packed decode: 2 x fp8(e4m3) -> 2 x f32 in ONE VALU instruction.
// HI must be a compile-time constant: the builtin's byte-select operand is
// an immediate (R15 failed passing a runtime bool) -> template parameter.
template <bool HI>
__device__ __forceinline__ v2f fp8x2(unsigned int w) {
#if __has_builtin(__builtin_amdgcn_cvt_pk_f32_fp8)
    return __builtin_amdgcn_cvt_pk_f32_fp8((int)w, HI);
#else
    unsigned int b = HI ? (w >> 16) : w;
    __half_raw h0 = __hip_cvt_fp8_to_halfraw((__hip_fp8_storage_t)(b & 0xFF), __HIP_E4M3);
    __half_raw h1 = __hip_cvt_fp8_to_halfraw((__hip_fp8_storage_t)((b >> 8) & 0xFF), __HIP_E4M3);
    v2f r; r.x = __half2float(__half(h0)); r.y = __half2float(__half(h1));
    return r;
#endif
}

// ===========================================================================
// CSR build, XCD-partitioned (R10) + int4-vectorized edge reads:
// 4 edges per load instruction; grid = FILL_CHUNKS x 8.
// ===========================================================================
__global__ __launch_bounds__(256) void histogram_xcd_kernel(
    const int4* __restrict__ dst4, int* __restrict__ deg)
{
    int part = blockIdx.x & 7;
    int lo = part * PART_SZ, hi = lo + PART_SZ;
    int base = (blockIdx.x >> 3) * CHUNK_I4;
    for (int i = threadIdx.x; i < CHUNK_I4; i += 256) {
        int4 d = dst4[base + i];
        if (d.x >= lo && d.x < hi) atomicAdd(&deg[d.x], 1);
        if (d.y >= lo && d.y < hi) atomicAdd(&deg[d.y], 1);
        if (d.z >= lo && d.z < hi) atomicAdd(&deg[d.z], 1);
        if (d.w >= lo && d.w < hi) atomicAdd(&deg[d.w], 1);
    }
}

__global__ __launch_bounds__(256) void fill_xcd_kernel(
    const int4* __restrict__ src4, const int4* __restrict__ dst4,
    int* __restrict__ cursor, int* __restrict__ nbr)
{
    int part = blockIdx.x & 7;
    int lo = part * PART_SZ, hi = lo + PART_SZ;
    int base = (blockIdx.x >> 3) * CHUNK_I4;
    for (int i = threadIdx.x; i < CHUNK_I4; i += 256) {
        int4 d = dst4[base + i];
        int4 s = src4[base + i];
        if (d.x >= lo && d.x < hi) { int p = atomicAdd(&cursor[d.x], 1); nbr[p] = s.x; }
        if (d.y >= lo && d.y < hi) { int p = atomicAdd(&cursor[d.y], 1); nbr[p] = s.y; }
        if (d.z >= lo && d.z < hi) { int p = atomicAdd(&cursor[d.z], 1); nbr[p] = s.z; }
        if (d.w >= lo && d.w < hi) { int p = atomicAdd(&cursor[d.w], 1); nbr[p] = s.w; }
    }
}

__global__ __launch_bounds__(1024) void scan1_kernel(
    const int* __restrict__ deg, int* __restrict__ offs, int* __restrict__ bsum)
{
    __shared__ int tmp[1024];
    int gid = blockIdx.x * 1024 + threadIdx.x;
    int v = (gid < N_NODES) ? deg[gid] : 0;
    tmp[threadIdx.x] = v;
    __syncthreads();
    for (int off = 1; off < 1024; off <<= 1) {
        int t = (threadIdx.x >= off) ? tmp[threadIdx.x - off] : 0;
        __syncthreads();
        tmp[threadIdx.x] += t;
        __syncthreads();
    }
    if (gid < N_NODES) offs[gid] = tmp[threadIdx.x] - v;
    if (threadIdx.x == 1023) bsum[blockIdx.x] = tmp[1023];
}

// scan3b: each block redundantly reduces bsum for its base offset.
__global__ __launch_bounds__(1024) void scan3b_kernel(
    int* __restrict__ offs, const int* __restrict__ bsum, int* __restrict__ cursor)
{
    __shared__ int red[128];
    int tid = threadIdx.x;
    if (tid < 128) red[tid] = (tid < (int)blockIdx.x && tid < NB_SCAN) ? bsum[tid] : 0;
    __syncthreads();
    if (tid < 64) red[tid] += red[tid + 64];
    __syncthreads();
    if (tid < 32) red[tid] += red[tid + 32];
    __syncthreads();
    if (tid < 16) red[tid] += red[tid + 16];
    __syncthreads();
    if (tid < 8)  red[tid] += red[tid + 8];
    __syncthreads();
    if (tid < 4)  red[tid] += red[tid + 4];
    __syncthreads();
    if (tid < 2)  red[tid] += red[tid + 2];
    __syncthreads();
    if (tid == 0) red[0] += red[1];
    __syncthreads();
    int base = red[0];
    int gid = blockIdx.x * 1024 + tid;
    if (gid < N_NODES) {
        int v = offs[gid] + base;
        offs[gid] = v;
        cursor[gid] = v;
    }
    if (gid == N_NODES) offs[N_NODES] = N_EDGES;
}

// ===========================================================================
// dense1_lin: u(fp8 e4m3, 64B rows = 1 line) = x @ W1l^T ;
// hv(f32) = x @ W1r^T + b1.
// ===========================================================================
__global__ __launch_bounds__(256) void dense1_lin_kernel(
    const float* __restrict__ x, const float* __restrict__ W1l,
    const float* __restrict__ W1r, const float* __restrict__ b1,
    unsigned char* __restrict__ u8, float* __restrict__ hv)
{
    __shared__ float wlT[64 * 65];
    __shared__ float wrT[64 * 65];
    for (int idx = threadIdx.x; idx < 4096; idx += 256) {
        int f = idx >> 6, k = idx & 63;
        wlT[k * 65 + f] = W1l[idx];
        wrT[k * 65 + f] = W1r[idx];
    }
    __syncthreads();

    int f  = threadIdx.x & 63;
    int wv = threadIdx.x >> 6;
    float wl[64], wr[64];
#pragma unroll
    for (int k = 0; k < 64; ++k) {
        wl[k] = wlT[k * 65 + f];
        wr[k] = wrT[k * 65 + f];
    }
    float bias = b1[f];
    int node0 = blockIdx.x * 64;

    for (int nn = 0; nn < 16; ++nn) {
        int node = node0 + nn * 4 + wv;          // wave-uniform
        if (node < N_NODES) {
            float xv = x[(size_t)node * 64 + f];
            float ua = 0.f, va = bias;
#pragma unroll
            for (int k = 0; k < 64; ++k) {
                float xb = bcast(xv, k);
                ua += xb * wl[k];
                va += xb * wr[k];
            }
            u8[(size_t)node * 64 + f] = f2fp8(ua);   // coalesced 64B/node
            hv[(size_t)node * 64 + f] = va;
        }
    }
}

// ===========================================================================
// gather1_bn v8 (R14, proven 109 us — structure frozen): v3 shape + fp8
// rows (1 line/edge) + HW packed decode; invalid edges zero the packed word.
// ===========================================================================
__global__ __launch_bounds__(256) void gather1_bn_kernel(
    const unsigned short* __restrict__ u16, const int* __restrict__ offs,
    const int* __restrict__ nbr, float* __restrict__ hv,
    float* __restrict__ sums, float* __restrict__ sumsq)
{
    int lane = threadIdx.x & 63;
    int m    = lane & 31;
    int half = lane >> 5;
    int wv   = threadIdx.x >> 6;
    int node0 = blockIdx.x * 64;
    float s1_0 = 0.f, s1_1 = 0.f, s2_0 = 0.f, s2_1 = 0.f;

    for (int nn = 0; nn < 16; ++nn) {
        int node = node0 + nn * 4 + wv;
        if (node < N_NODES) {                    // wave-uniform
            int beg = offs[node], end = offs[node + 1];
            int deg = end - beg;
            float p0=0,p1=0,p2=0,p3=0,q0=0,q1=0,q2=0,q3=0;
            for (int c = 0; c < deg; c += 64) {  // ~always 1 iteration
                int idx = beg + c + lane;
                int id  = nbr[(idx < end) ? idx : (end - 1)];  // coalesced
                int cnt = min(deg - c, 64);
                for (int r = 0; r < cnt; r += 16) {   // wave-uniform trips
#pragma unroll
                    for (int i = 0; i < 8; ++i) {
                        int e   = r + 2 * i + half;   // < 64 always
                        int ide = __shfl(id, e);      // id from registers
                        unsigned int w = u16[(size_t)ide * 32 + m];
                        w = (e < cnt) ? w : 0u;       // mask packed word
                        v2f d = fp8x2<false>(w);      // 1 HW instruction
                        if ((i & 3) == 0)      { p0 += d.x; q0 += d.y; }
                        else if ((i & 3) == 1) { p1 += d.x; q1 += d.y; }
                        else if ((i & 3) == 2) { p2 += d.x; q2 += d.y; }
                        else                   { p3 += d.x; q3 += d.y; }
                    }
                }
            }
            float P = (p0 + p1) + (p2 + p3);
            float Q = (q0 + q1) + (q2 + q3);
            P += __shfl_xor(P, 32);    // combine the two half-waves
            Q += __shfl_xor(Q, 32);
            if (half == 0) {
                float inv = 1.0f / (float)max(deg, 1);
                float2 v = ((const float2*)hv)[(size_t)node * 32 + m];
                float h0 = P * inv + v.x;
                float h1 = Q * inv + v.y;
                ((float2*)hv)[(size_t)node * 32 + m] = make_float2(h0, h1);
                s1_0 += h0; s1_1 += h1;
                s2_0 += h0 * h0; s2_1 += h1 * h1;
            }
        }
    }

    __shared__ float2 redA[256];
    __shared__ float2 redB[256];
    redA[threadIdx.x] = make_float2(s1_0, s1_1);
    redB[threadIdx.x] = make_float2(s2_0, s2_1);
    __syncthreads();
    if (threadIdx.x < 32) {
        int mm = threadIdx.x;
        float a0=0,a1=0,b0=0,b1=0;
        for (int w = 0; w < 4; ++w) {
            float2 A = redA[w * 64 + mm]; a0 += A.x; a1 += A.y;
            float2 B = redB[w * 64 + mm]; b0 += B.x; b1 += B.y;
        }
        atomicAdd(&sums[2 * mm], a0);  atomicAdd(&sums[2 * mm + 1], a1);
        atomicAdd(&sumsq[2 * mm], b0); atomicAdd(&sumsq[2 * mm + 1], b1);
    }
}

// ===========================================================================
// dense2_bn: BN finalize folded in; BN+ReLU per lane; projection tmp is
// ONE fp8 row per node (40B used, 64B stride = 1 line); out direct.
// ===========================================================================
__global__ __launch_bounds__(256) void dense2_bn_kernel(
    const float* __restrict__ h, const float* __restrict__ sums,
    const float* __restrict__ sumsq, const float* __restrict__ gamma,
    const float* __restrict__ beta, const float* __restrict__ W2l,
    const float* __restrict__ W2r, const float* __restrict__ b2,
    unsigned char* __restrict__ t40, float* __restrict__ out)
{
    __shared__ float wlT[64 * 65];
    __shared__ float wrT[64 * 65];
    for (int idx = threadIdx.x; idx < 2560; idx += 256) {
        int f = idx >> 6, k = idx & 63;      // f < 40
        wlT[k * 65 + f] = W2l[idx];
        wrT[k * 65 + f] = W2r[idx];
    }
    __syncthreads();

    int f  = threadIdx.x & 63;
    int wv = threadIdx.x >> 6;
    int fc = (f < 40) ? f : 39;
    float wl[64], wr[64];
#pragma unroll
    for (int k = 0; k < 64; ++k) {
        wl[k] = wlT[k * 65 + fc];
        wr[k] = wrT[k * 65 + fc];
    }
    float bias = b2[fc];

    // BN finalize (redundant per block, ~10 insts)
    float inv_n = 1.0f / (float)N_NODES;
    float mu  = sums[f] * inv_n;
    float var = sumsq[f] * inv_n - mu * mu;
    float rs  = rsqrtf(var + BN_EPS);
    float sc  = gamma[f] * rs;
    float sh  = beta[f] - mu * sc;

    int node0 = blockIdx.x * 64;

    for (int nn = 0; nn < 16; ++nn) {
        int node = node0 + nn * 4 + wv;          // wave-uniform
        if (node < N_NODES) {
            float hvv = h[(size_t)node * 64 + f];
            float hn  = fmaxf(hvv * sc + sh, 0.f);   // BN + ReLU fused
            float ta = 0.f, ra = bias;
#pragma unroll
            for (int k = 0; k < 64; ++k) {
                float hb = bcast(hn, k);
                ta += hb * wl[k];
                ra += hb * wr[k];
            }
            if (f < 40) {
                t40[(size_t)node * 64 + f] = f2fp8(ta);
                out[(size_t)node * 40 + f] = ra;
            }
        }
    }
}

// ===========================================================================
// gather2 v7: out += mean(t40[nbr]); t40 fp8, 40B used / 64B stride = ONE
// line per edge. Quarter-wave shape: 4 dword loads per 16-edge round
// (4 edges each; lane m<10 covers the row, m>=10 clamped to the same line).
// HW packed decode; invalid edges zero the word. Uniform flow; only the
// final store is predicated.
// ===========================================================================
__global__ __launch_bounds__(256) void gather2_kernel(
    const unsigned int* __restrict__ t40, const int* __restrict__ offs,
    const int* __restrict__ nbr, float* __restrict__ out)
{
    int lane = threadIdx.x & 63;
    int q    = lane >> 4;          // quarter 0..3
    int m    = lane & 15;          // dword in row; cl<10 used (feats 4cl..4cl+3)
    int cl   = (m < 10) ? m : 9;
    int wv   = threadIdx.x >> 6;
    int node0 = blockIdx.x * 64;

    for (int nn = 0; nn < 16; ++nn) {
        int node = node0 + nn * 4 + wv;
        if (node < N_NODES) {                    // wave-uniform
            int beg = offs[node], end = offs[node + 1];
            int deg = end - beg;
            float a0=0,a1=0,a2=0,a3=0, b0=0,b1=0,b2=0,b3=0;
            for (int c = 0; c < deg; c += 64) {
                int idx = beg + c + lane;
                int id  = nbr[(idx < end) ? idx : (end - 1)];  // coalesced
                int cnt = min(deg - c, 64);
                for (int r = 0; r < cnt; r += 16) {
#pragma unroll
                    for (int i = 0; i < 4; ++i) {   // 4 instrs x 4 edges
                        int e   = r + 4 * i + q;
                        int ide = __shfl(id, min(e, cnt - 1));
                        unsigned int w = t40[(size_t)ide * 16 + cl];
                        w = (e < cnt) ? w : 0u;     // mask packed word
                        v2f dlo = fp8x2<false>(w);
                        v2f dhi = fp8x2<true>(w);
                        if (i & 1) { b0 += dlo.x; b1 += dlo.y; b2 += dhi.x; b3 += dhi.y; }
                        else       { a0 += dlo.x; a1 += dlo.y; a2 += dhi.x; a3 += dhi.y; }
                    }
                }
            }
            a0 += b0; a1 += b1; a2 += b2; a3 += b3;
            // combine quarters (all lanes active)
            a0 += __shfl_xor(a0, 16); a0 += __shfl_xor(a0, 32);
            a1 += __shfl_xor(a1, 16); a1 += __shfl_xor(a1, 32);
            a2 += __shfl_xor(a2, 16); a2 += __shfl_xor(a2, 32);
            a3 += __shfl_xor(a3, 16); a3 += __shfl_xor(a3, 32);
            if (lane < 10) {          // quarter 0, dwords 0..9 = feats 4m..4m+3
                float inv = 1.0f / (float)max(deg, 1);
                float4 o = ((float4*)out)[(size_t)node * 10 + m];
                o.x += a0 * inv;
                o.y += a1 * inv;
                o.z += a2 * inv;
                o.w += a3 * inv;
                ((float4*)out)[(size_t)node * 10 + m] = o;
            }
        }
    }
}

extern "C" void kernel_launch(void* const* d_in, const int* in_sizes, int n_in,
                              void* d_out, int out_size, void* d_ws, size_t ws_size,
                              hipStream_t stream)
{
    const float* x     = (const float*)d_in[0];
    const int*   ei    = (const int*)d_in[1];
    const float* W1l   = (const float*)d_in[2];
    const float* W1r   = (const float*)d_in[3];
    const float* b1    = (const float*)d_in[4];
    const float* gamma = (const float*)d_in[5];
    const float* beta  = (const float*)d_in[6];
    const float* W2l   = (const float*)d_in[7];
    const float* W2r   = (const float*)d_in[8];
    const float* b2    = (const float*)d_in[9];
    float* out = (float*)d_out;

    const int4* src4 = (const int4*)ei;              // edge_index[0], 16B-aligned
    const int4* dst4 = (const int4*)(ei + N_EDGES);  // edge_index[1]

    // workspace layout (~39 MB; 58.8 MB available). 64B-aligned arrays.
    float* ws    = (float*)d_ws;
    float* hv    = ws;                               // f32 [N*64]
    float* sums  = hv + (size_t)N_NODES * 64;        // 64
    float* sumsq = sums + 64;                        // 64
    float* padf  = sumsq + 64;                       // 128 pad
    int* deg    = (int*)(padf + 128);                // N
    int* offs   = deg + N_NODES;                     // N+16 (padded)
    int* cursor = offs + N_NODES + 16;               // N
    int* bsum   = cursor + N_NODES;                  // 128
    // scratch: u8 (fp8 N*64B) until gather1; t40 (fp8 N*64B) reuses it.
    unsigned char* u8 = (unsigned char*)(bsum + 128);
    unsigned char* t40 = u8;
    int* nbr    = (int*)(u8 + (size_t)N_NODES * 64); // E

    dim3 blk(256);

    // ---- CSR build (XCD-partitioned, int4 reads) + stat zeroing ----
    (void)hipMemsetAsync(sums, 0, (size_t)(256 + N_NODES) * sizeof(int), stream);
    histogram_xcd_kernel<<<FILL_CHUNKS * 8, blk, 0, stream>>>(dst4, deg);
    scan1_kernel<<<NB_SCAN, 1024, 0, stream>>>(deg, offs, bsum);
    scan3b_kernel<<<NB_SCAN, 1024, 0, stream>>>(offs, bsum, cursor);
    fill_xcd_kernel<<<FILL_CHUNKS * 8, blk, 0, stream>>>(src4, dst4, cursor, nbr);

    int dblocks = (N_NODES + 63) / 64;
    int gblocks = (N_NODES + 63) / 64;

    // ---- layer 1 ----
    dense1_lin_kernel<<<dblocks, blk, 0, stream>>>(x, W1l, W1r, b1, u8, hv);
    gather1_bn_kernel<<<gblocks, blk, 0, stream>>>(
        (const unsigned short*)u8, offs, nbr, hv, sums, sumsq);

    // ---- layer 2 (BN finalize + BN+ReLU fused into dense2) ----
    dense2_bn_kernel<<<dblocks, blk, 0, stream>>>(
        hv, sums, sumsq, gamma, beta, W2l, W2r, b2, t40, out);
    gather2_kernel<<<gblocks, blk, 0, stream>>>(
        (const unsigned int*)t40, offs, nbr, out);
}